// Round 8
// baseline (125.247 us; speedup 1.0000x reference)
//
#include <hip/hip_runtime.h>
#include <stdint.h>

typedef unsigned short u16;
typedef __bf16 bf16x8 __attribute__((ext_vector_type(8)));
typedef __bf16 bf16x4 __attribute__((ext_vector_type(4)));
typedef short s16x4 __attribute__((ext_vector_type(4)));
typedef _Float16 f16x4 __attribute__((ext_vector_type(4)));
typedef _Float16 f16x8 __attribute__((ext_vector_type(8)));
typedef float  f32x4  __attribute__((ext_vector_type(4)));

__device__ __forceinline__ u16 f2bf(float f) {
  union { float f; unsigned u; } v; v.f = f;
  unsigned r = v.u + 0x7FFFu + ((v.u >> 16) & 1u);
  return (u16)(r >> 16);
}

__device__ __forceinline__ void gload16(const void* g, void* l) {
  __builtin_amdgcn_global_load_lds((const __attribute__((address_space(1))) unsigned int*)g,
                                   (__attribute__((address_space(3))) unsigned int*)l, 16, 0, 0);
}

__device__ __forceinline__ f32x4 mfma32(bf16x8 a, bf16x8 b, f32x4 c) {
  return __builtin_amdgcn_mfma_f32_16x16x32_bf16(a, b, c, 0, 0, 0);
}

// ---------------- fused prep: x->bf16 convert + both weight transposes ----------------
__global__ void k_prep(const float* __restrict__ x, const float* __restrict__ qw,
                       const float* __restrict__ pjw, u16* __restrict__ Xb,
                       u16* __restrict__ Wt, u16* __restrict__ Pt) {
  __shared__ u16 tile[64][65];
  const int b = blockIdx.x, t = threadIdx.x;
  if (b < 2048) {
    int i = b * 256 + t;
    float4 v = ((const float4*)x)[i];
    uint2 o;
    o.x = (unsigned)f2bf(v.x) | ((unsigned)f2bf(v.y) << 16);
    o.y = (unsigned)f2bf(v.z) | ((unsigned)f2bf(v.w) << 16);
    ((uint2*)Xb)[i] = o;
    return;
  }
  const float* in; u16* out; int Cc, bx, by;
  if (b < 2240) { in = qw;  out = Wt; Cc = 1536; bx = (b - 2048) % 24; by = (b - 2048) / 24; }
  else          { in = pjw; out = Pt; Cc = 512;  bx = (b - 2240) & 7;  by = (b - 2240) >> 3; }
  const int c0 = bx * 64, r0 = by * 64;
  #pragma unroll
  for (int i = 0; i < 16; ++i) {
    int idx = t + i * 256;
    int r = idx >> 6, c = idx & 63;
    tile[c][r] = f2bf(in[(size_t)(r0 + r) * Cc + c0 + c]);
  }
  __syncthreads();
  #pragma unroll
  for (int i = 0; i < 16; ++i) {
    int idx = t + i * 256;
    int r = idx >> 6, c = idx & 63;
    out[(size_t)(c0 + r) * 512 + r0 + c] = tile[r][c];
  }
}

// swizzle for [rows][32] bf16 tiles: chunk 0..3 (16B units), returns u16 index
__device__ __forceinline__ int swz32(int row, int chunk) {
  return row * 32 + ((chunk ^ ((row >> 1) & 3)) << 3);
}
// swizzle for [rows][64] bf16 tiles (128B rows): colByte within row, returns u16 index
__device__ __forceinline__ int swz64(int row, int colByte) {
  return (row * 128 + (colByte ^ ((row & 7) << 4))) >> 1;
}
// K-buffer swizzle: QK^T reads use permuted rows varying in row bits {0,1,3}; XOR those
// bits into the 16B-slot index (slot bits 4,5,6 of byte) for bank uniformity.
__device__ __forceinline__ int swzK(int row, int colByte) {
  return (row * 128 + (colByte ^ ((row & 3) << 4) ^ (((row >> 3) & 1) << 6))) >> 1;
}

// ---------------- GEMM core: C[BM x BN] tile, K=512 (lda=ldb=512), BK=32, gload_lds ----
template<int BM, int BN>
__device__ __forceinline__ void gemm_core(const u16* __restrict__ A, const u16* __restrict__ Bt,
                                          int m0, int n0, f32x4 (&acc)[BM/32][BN/32],
                                          u16* lA, u16* lB) {
  const int t = threadIdx.x;
  const int lane = t & 63;
  const int w = t >> 6, wr = w >> 1, wc = w & 1;
  const int lr = lane & 15, lg = lane >> 4;
  char* lAb = (char*)lA + w * 1024;
  char* lBb = (char*)lB + w * 1024;
  #pragma unroll 1
  for (int k0 = 0; k0 < 512; k0 += 32) {
    __syncthreads();
    #pragma unroll
    for (int u = 0; u < BM / 64; ++u) {
      int id = u * 256 + t, row = id >> 2, gc = (id & 3) ^ ((row >> 1) & 3);
      gload16(A + (size_t)(m0 + row) * 512 + k0 + gc * 8, lAb + u * 4096);
    }
    #pragma unroll
    for (int u = 0; u < BN / 64; ++u) {
      int id = u * 256 + t, row = id >> 2, gc = (id & 3) ^ ((row >> 1) & 3);
      gload16(Bt + (size_t)(n0 + row) * 512 + k0 + gc * 8, lBb + u * 4096);
    }
    __syncthreads();
    bf16x8 af[BM / 32], bfr[BN / 32];
    #pragma unroll
    for (int i = 0; i < BM / 32; ++i)
      af[i] = __builtin_bit_cast(bf16x8, *(const uint4*)&lA[swz32(wr * (BM / 2) + i * 16 + lr, lg)]);
    #pragma unroll
    for (int j = 0; j < BN / 32; ++j)
      bfr[j] = __builtin_bit_cast(bf16x8, *(const uint4*)&lB[swz32(wc * (BN / 2) + j * 16 + lr, lg)]);
    #pragma unroll
    for (int i = 0; i < BM / 32; ++i)
      #pragma unroll
      for (int j = 0; j < BN / 32; ++j)
        acc[i][j] = __builtin_amdgcn_mfma_f32_16x16x32_bf16(af[i], bfr[j], acc[i][j], 0, 0, 0);
  }
}

// ---------------- QKV GEMM (128x64 tile) + LDS-staged coalesced scatter --------------
__global__ __launch_bounds__(256, 2) void k_gemm_qkv(const u16* __restrict__ A, const u16* __restrict__ Bt,
                                                     const float* __restrict__ bias,
                                                     u16* __restrict__ Qb, u16* __restrict__ Kb,
                                                     u16* __restrict__ Vtb) {
  __shared__ __align__(16) u16 lA[128 * 32];
  __shared__ __align__(16) u16 lB[64 * 32];
  __shared__ __align__(16) u16 vt[9216];  // Q/K: [128][72]; V: [64][136]
  f32x4 acc[4][2];
  #pragma unroll
  for (int i = 0; i < 4; ++i)
    #pragma unroll
    for (int j = 0; j < 2; ++j) acc[i][j] = (f32x4){0.f, 0.f, 0.f, 0.f};
  const int m0 = blockIdx.x * 128, n0 = blockIdx.y * 64;
  gemm_core<128, 64>(A, Bt, m0, n0, acc, lA, lB);
  const int t = threadIdx.x;
  const int lane = t & 63;
  const int w = t >> 6, wr = w >> 1, wc = w & 1;
  const int lr = lane & 15, lg = lane >> 4;
  const int which = n0 >> 9, h = (n0 >> 6) & 7;
  const int b = m0 >> 11, m0l = m0 & 2047;
  const size_t bh = (size_t)(b * 8 + h);
  if (which != 2) {
    const float scl = (which == 0) ? 0.18033688011112042f : 1.0f;  // Q: 0.125*log2e
    #pragma unroll
    for (int i = 0; i < 4; ++i)
      #pragma unroll
      for (int j = 0; j < 2; ++j) {
        int n = n0 + wc * 32 + j * 16 + lr;
        float bb = bias[n];
        #pragma unroll
        for (int r = 0; r < 4; ++r)
          vt[(wr * 64 + i * 16 + lg * 4 + r) * 72 + wc * 32 + j * 16 + lr] =
              f2bf((acc[i][j][r] + bb) * scl);
      }
    __syncthreads();
    u16* dst = (which == 0 ? Qb : Kb) + (bh * 2048 + m0l) * 64;
    #pragma unroll
    for (int it = 0; it < 4; ++it) {
      int unit = it * 256 + t, row = unit >> 3, ch = unit & 7;
      *(uint4*)&dst[row * 64 + ch * 8] = *(const uint4*)&vt[row * 72 + ch * 8];
    }
  } else {
    #pragma unroll
    for (int i = 0; i < 4; ++i)
      #pragma unroll
      for (int j = 0; j < 2; ++j) {
        int n = n0 + wc * 32 + j * 16 + lr;
        float bb = bias[n];
        uint2 pk;
        pk.x = (unsigned)f2bf(acc[i][j][0] + bb) | ((unsigned)f2bf(acc[i][j][1] + bb) << 16);
        pk.y = (unsigned)f2bf(acc[i][j][2] + bb) | ((unsigned)f2bf(acc[i][j][3] + bb) << 16);
        *(uint2*)&vt[(wc * 32 + j * 16 + lr) * 136 + wr * 64 + i * 16 + lg * 4] = pk;
      }
    __syncthreads();
    u16* dst = Vtb + bh * 64 * 2048 + m0l;
    #pragma unroll
    for (int it = 0; it < 4; ++it) {
      int unit = it * 256 + t, row = unit >> 4, ch = unit & 15;
      *(uint4*)&dst[(size_t)row * 2048 + ch * 8] = *(const uint4*)&vt[row * 136 + ch * 8];
    }
  }
}

// ---------------- proj GEMM (64x64 tile) -> fp32 output ----------------
__global__ __launch_bounds__(256, 2) void k_gemm_proj(const u16* __restrict__ A, const u16* __restrict__ Bt,
                                                      const float* __restrict__ bias,
                                                      float* __restrict__ out) {
  __shared__ __align__(16) u16 lA[64 * 32];
  __shared__ __align__(16) u16 lB[64 * 32];
  f32x4 acc[2][2];
  #pragma unroll
  for (int i = 0; i < 2; ++i)
    #pragma unroll
    for (int j = 0; j < 2; ++j) acc[i][j] = (f32x4){0.f, 0.f, 0.f, 0.f};
  const int m0 = blockIdx.x * 64, n0 = blockIdx.y * 64;
  gemm_core<64, 64>(A, Bt, m0, n0, acc, lA, lB);
  const int lane = threadIdx.x & 63;
  const int w = threadIdx.x >> 6, wr = w >> 1, wc = w & 1;
  const int lr = lane & 15, lg = lane >> 4;
  #pragma unroll
  for (int i = 0; i < 2; ++i)
    #pragma unroll
    for (int j = 0; j < 2; ++j)
      #pragma unroll
      for (int r = 0; r < 4; ++r) {
        int m = m0 + wr * 32 + i * 16 + lg * 4 + r;
        int n = n0 + wc * 32 + j * 16 + lr;
        out[(size_t)m * 512 + n] = acc[i][j][r] + bias[n];
      }
}

// ---------------- flash attention: static-max softmax, 32 q/wave, KV-split=4 ---------
// All-K=32 MFMA pipeline. QK^T A-rows are PERMUTED (even/odd 4-row groups) so the D
// layout lands P at lane k-slots s = lg*8 + j, which is exactly the 16x16x32 B-operand
// k-map -> PV runs at full K=32 rate straight from registers. l via ones-row MFMA.
__global__ __launch_bounds__(256, 4) void k_attn(const u16* __restrict__ Qb, const u16* __restrict__ Kb,
                                                 const u16* __restrict__ Vtb,
                                                 u16* __restrict__ Op, float* __restrict__ Lp) {
  __shared__ __align__(16) u16 smem[16384];  // Kt dbuf (16KB) + Vl dbuf (16KB); reused by epilogue
  u16* Kt0 = smem;
  u16* Kt1 = smem + 4096;
  u16* Vl0 = smem + 8192;
  u16* Vl1 = smem + 12288;
  const int t = threadIdx.x;
  const int lane = t & 63, w = t >> 6;
  const int lr = lane & 15, lg = lane >> 4;
  // flat 1024-block grid -> (qtile, bh, split) with XCD grouping
  const int f = blockIdx.x;
  const int xc = f & 7, j = f >> 3;
  const int group = xc + ((j >> 4) << 3);
  const int qtile = j & 15, bh = group & 15, split = group >> 4;
  const int q0 = qtile * 128 + w * 32;   // wave owns 32 q-rows
  const int sBeg = split * 512;

  bf16x8 qf[2][2];  // [c][half]: B-operand frags, col=q (c*16+lr), k=lg*8+j
  #pragma unroll
  for (int c = 0; c < 2; ++c) {
    const u16* qrow = Qb + ((size_t)bh * 2048 + q0 + c * 16 + lr) * 64;
    qf[c][0] = __builtin_bit_cast(bf16x8, *(const uint4*)(qrow + lg * 8));
    qf[c][1] = __builtin_bit_cast(bf16x8, *(const uint4*)(qrow + 32 + lg * 8));
  }

  f32x4 oacc[2][4], lacc[2];
  #pragma unroll
  for (int c = 0; c < 2; ++c) {
    lacc[c] = (f32x4){0.f, 0.f, 0.f, 0.f};
    #pragma unroll
    for (int ff = 0; ff < 4; ++ff) oacc[c][ff] = (f32x4){0.f, 0.f, 0.f, 0.f};
  }
  bf16x8 ones8;
  #pragma unroll
  for (int k = 0; k < 8; ++k) ones8[k] = (__bf16)1.f;
  const f32x4 NEG12 = (f32x4){-12.f, -12.f, -12.f, -12.f};

  // permuted K row for QK^T A-operand: parity p MFMA covers rows p*4 + (lr>>2)*8 + (lr&3)
  const int prowBase = ((lr >> 2) << 3) + (lr & 3);

  const int r0_ = t >> 3, o0 = (t & 7) << 3;
  const int r1_ = r0_ + 32;
  const int sK0 = swzK(r0_, o0 * 2), sK1 = swzK(r1_, o0 * 2);
  const int sV0 = swz64(r0_, o0 * 2), sV1 = swz64(r1_, o0 * 2);
  const u16* Kbase = Kb + (size_t)bh * 2048 * 64;
  const u16* Vbase = Vtb + (size_t)bh * 64 * 2048;
  const u16* kp0 = Kbase + (size_t)(sBeg + r0_) * 64 + o0;
  const u16* kp1 = Kbase + (size_t)(sBeg + r1_) * 64 + o0;
  const u16* vp0 = Vbase + (size_t)r0_ * 2048 + sBeg + o0;
  const u16* vp1 = Vbase + (size_t)r1_ * 2048 + sBeg + o0;

  uint4 kq0, kq1, vq0, vq1;
  // prologue: tile0 -> regs -> buf0; tile1 -> regs
  kq0 = *(const uint4*)kp0; kq1 = *(const uint4*)kp1;
  vq0 = *(const uint4*)vp0; vq1 = *(const uint4*)vp1;
  kp0 += 4096; kp1 += 4096; vp0 += 64; vp1 += 64;
  *(uint4*)&Kt0[sK0] = kq0; *(uint4*)&Kt0[sK1] = kq1;
  *(uint4*)&Vl0[sV0] = vq0; *(uint4*)&Vl0[sV1] = vq1;
  kq0 = *(const uint4*)kp0; kq1 = *(const uint4*)kp1;
  vq0 = *(const uint4*)vp0; vq1 = *(const uint4*)vp1;
  kp0 += 4096; kp1 += 4096; vp0 += 64; vp1 += 64;

  auto TILE = [&](u16* KC, u16* VC, u16* KN, u16* VN) {
    __syncthreads();  // KC/VC fully staged; KN/VN free to overwrite
    // S^T = K Q^T with permuted A rows; C-init = -12 (static softmax shift).
    // sa[c][j32][p][r] = S[s = j32*32 + lg*8 + p*4 + r][q = c*16+lr] - 12
    f32x4 sa[2][2][2];
    __builtin_amdgcn_s_setprio(1);
    #pragma unroll
    for (int j32 = 0; j32 < 2; ++j32)
      #pragma unroll
      for (int p = 0; p < 2; ++p) {
        const int prow = j32 * 32 + p * 4 + prowBase;
        bf16x8 kb0 = __builtin_bit_cast(bf16x8, *(const uint4*)&KC[swzK(prow, lg * 16)]);
        bf16x8 kb1 = __builtin_bit_cast(bf16x8, *(const uint4*)&KC[swzK(prow, 64 + lg * 16)]);
        #pragma unroll
        for (int c = 0; c < 2; ++c) {
          f32x4 z = mfma32(kb0, qf[c][0], NEG12);
          sa[c][j32][p] = mfma32(kb1, qf[c][1], z);
        }
      }
    __builtin_amdgcn_s_setprio(0);
    // stage next tile (regs -> LDS), then prefetch tile+2 (global -> regs)
    *(uint4*)&KN[sK0] = kq0; *(uint4*)&KN[sK1] = kq1;
    *(uint4*)&VN[sV0] = vq0; *(uint4*)&VN[sV1] = vq1;
    kq0 = *(const uint4*)kp0; kq1 = *(const uint4*)kp1;
    vq0 = *(const uint4*)vp0; vq1 = *(const uint4*)vp1;
    kp0 += 4096; kp1 += 4096; vp0 += 64; vp1 += 64;
    // p = 2^(s-12), packed 8-wide: pb[c][j32][k= p*4+r]
    bf16x8 pb[2][2];
    #pragma unroll
    for (int c = 0; c < 2; ++c)
      #pragma unroll
      for (int j32 = 0; j32 < 2; ++j32)
        #pragma unroll
        for (int p = 0; p < 2; ++p)
          #pragma unroll
          for (int r = 0; r < 4; ++r)
            pb[c][j32][p * 4 + r] = (__bf16)exp2f(sa[c][j32][p][r]);
    // O^T += V P^T (K=32, P lane-local); l via ones-row MFMA
    __builtin_amdgcn_s_setprio(1);
    #pragma unroll
    for (int j32 = 0; j32 < 2; ++j32) {
      lacc[0] = mfma32(ones8, pb[0][j32], lacc[0]);
      lacc[1] = mfma32(ones8, pb[1][j32], lacc[1]);
      #pragma unroll
      for (int ff = 0; ff < 4; ++ff) {
        bf16x8 va = __builtin_bit_cast(bf16x8, *(const uint4*)&VC[swz64(ff * 16 + lr, j32 * 64 + lg * 16)]);
        oacc[0][ff] = mfma32(va, pb[0][j32], oacc[0][ff]);
        oacc[1][ff] = mfma32(va, pb[1][j32], oacc[1][ff]);
      }
    }
    __builtin_amdgcn_s_setprio(0);
  };

  #pragma unroll 1
  for (int tt = 0; tt < 4; ++tt) {
    TILE(Kt0, Vl0, Kt1, Vl1);
    TILE(Kt1, Vl1, Kt0, Vl0);
  }

  // ---- epilogue: stage fp16 partials in LDS [128][72], then full-line Op writes ----
  __syncthreads();  // all K/V LDS reads done; smem reusable
  #pragma unroll
  for (int c = 0; c < 2; ++c) {
    const int ql = w * 32 + c * 16 + lr;
    #pragma unroll
    for (int ff = 0; ff < 4; ++ff) {
      f16x4 hv;
      hv[0] = (_Float16)oacc[c][ff][0]; hv[1] = (_Float16)oacc[c][ff][1];
      hv[2] = (_Float16)oacc[c][ff][2]; hv[3] = (_Float16)oacc[c][ff][3];
      *(uint2*)&smem[ql * 72 + ff * 16 + lg * 4] = __builtin_bit_cast(uint2, hv);
    }
  }
  __syncthreads();
  {
    u16* dst = Op + ((size_t)(split * 16 + bh) * 2048 + qtile * 128) * 64;
    #pragma unroll
    for (int it = 0; it < 4; ++it) {
      int unit = it * 256 + t, row = unit >> 3, ch = unit & 7;
      *(uint4*)&dst[row * 64 + ch * 8] = *(const uint4*)&smem[row * 72 + ch * 8];
    }
  }
  #pragma unroll
  for (int c = 0; c < 2; ++c) {
    if (lg == 0) {
      const size_t orow = (size_t)((split * 16 + bh) * 2048) + q0 + c * 16 + lr;
      Lp[orow] = lacc[c][0];  // all rows of lacc equal (ones-row MFMA)
    }
  }
}

// ---------------- combine 4 KV-splits (shared static max) -> AO bf16 ----------------
__global__ void k_combine(const u16* __restrict__ Op, const float* __restrict__ Lp,
                          u16* __restrict__ AO) {
  int idx = blockIdx.x * 256 + threadIdx.x;  // 32768 rows * 8 chunks
  int chunk = idx & 7, row = idx >> 3;
  float den = Lp[row] + Lp[32768 + row] + Lp[65536 + row] + Lp[98304 + row];
  float inv = 1.0f / den;
  float o[8];
  #pragma unroll
  for (int k = 0; k < 8; ++k) o[k] = 0.f;
  #pragma unroll
  for (int s = 0; s < 4; ++s) {
    uint4 u = ((const uint4*)Op)[(size_t)s * 262144 + row * 8 + chunk];
    f16x8 hv = __builtin_bit_cast(f16x8, u);
    #pragma unroll
    for (int k = 0; k < 8; ++k) o[k] += (float)hv[k];
  }
  bf16x8 bv;
  #pragma unroll
  for (int k = 0; k < 8; ++k) bv[k] = (__bf16)(o[k] * inv);
  int bh = row >> 11, q = row & 2047, bb = bh >> 3, h = bh & 7;
  *(uint4*)&AO[((size_t)(bb * 2048 + q)) * 512 + h * 64 + chunk * 8] = __builtin_bit_cast(uint4, bv);
}

extern "C" void kernel_launch(void* const* d_in, const int* in_sizes, int n_in,
                              void* d_out, int out_size, void* d_ws, size_t ws_size,
                              hipStream_t stream) {
  (void)in_sizes; (void)n_in; (void)out_size; (void)ws_size;
  const float* x      = (const float*)d_in[0];
  const float* qkv_w  = (const float*)d_in[1];
  const float* qkv_b  = (const float*)d_in[2];
  const float* proj_w = (const float*)d_in[3];
  const float* proj_b = (const float*)d_in[4];
  float* out = (float*)d_out;
  char* wsc = (char*)d_ws;
  // Lp overlaps the Xb region (Xb dead after k_gemm_qkv; Lp written by k_attn later).
  float* Lp  = (float*)(wsc + 0);        // [4][16][2048] f32 (524,288 B)
  u16*   Xb  = (u16*)(wsc + 0);          // 4096x512 bf16       (4,194,304 B)
  u16*   Wt  = (u16*)(wsc + 4194304);    // 1536x512 bf16 (W^T) (1,572,864 B)
  u16*   Pt  = (u16*)(wsc + 5767168);    // 512x512 bf16 (W^T)  (  524,288 B)
  u16*   Qb  = (u16*)(wsc + 6291456);    // [16][2048][64] bf16 (4,194,304 B)
  u16*   Kb  = (u16*)(wsc + 10485760);   // [16][2048][64] bf16
  u16*   Vtb = (u16*)(wsc + 14680064);   // [16][64][2048] bf16
  u16*   AO  = (u16*)(wsc + 18874368);   // 4096x512 bf16
  u16*   Op  = (u16*)(wsc + 23068672);   // [4][16][2048][64] fp16 (16,777,216 B) -> end 39,845,888

  k_prep<<<2304, 256, 0, stream>>>(x, qkv_w, proj_w, Xb, Wt, Pt);
  k_gemm_qkv<<<dim3(32, 24), 256, 0, stream>>>(Xb, Wt, qkv_b, Qb, Kb, Vtb);
  k_attn<<<1024, 256, 0, stream>>>(Qb, Kb, Vtb, Op, Lp);
  k_combine<<<1024, 256, 0, stream>>>(Op, Lp, AO);
  k_gemm_proj<<<dim3(64, 8), 256, 0, stream>>>(AO, Pt, proj_b, out);
}

// Round 9
// 63.246 us; speedup vs baseline: 1.9803x; 1.9803x over previous
//
#include <hip/hip_runtime.h>
#include <stdint.h>

typedef unsigned short u16;
typedef __bf16 bf16x8 __attribute__((ext_vector_type(8)));
typedef __bf16 bf16x4 __attribute__((ext_vector_type(4)));
typedef _Float16 f16x4 __attribute__((ext_vector_type(4)));
typedef _Float16 f16x8 __attribute__((ext_vector_type(8)));
typedef float  f32x4  __attribute__((ext_vector_type(4)));

__device__ __forceinline__ u16 f2bf(float f) {
  union { float f; unsigned u; } v; v.f = f;
  unsigned r = v.u + 0x7FFFu + ((v.u >> 16) & 1u);
  return (u16)(r >> 16);
}

__device__ __forceinline__ void gload16(const void* g, void* l) {
  __builtin_amdgcn_global_load_lds((const __attribute__((address_space(1))) unsigned int*)g,
                                   (__attribute__((address_space(3))) unsigned int*)l, 16, 0, 0);
}

__device__ __forceinline__ f32x4 mfma32(bf16x8 a, bf16x8 b, f32x4 c) {
  return __builtin_amdgcn_mfma_f32_16x16x32_bf16(a, b, c, 0, 0, 0);
}

// ---------------- fused prep: x->bf16 convert + both weight transposes ----------------
__global__ void k_prep(const float* __restrict__ x, const float* __restrict__ qw,
                       const float* __restrict__ pjw, u16* __restrict__ Xb,
                       u16* __restrict__ Wt, u16* __restrict__ Pt) {
  __shared__ u16 tile[64][65];
  const int b = blockIdx.x, t = threadIdx.x;
  if (b < 2048) {
    int i = b * 256 + t;
    float4 v = ((const float4*)x)[i];
    uint2 o;
    o.x = (unsigned)f2bf(v.x) | ((unsigned)f2bf(v.y) << 16);
    o.y = (unsigned)f2bf(v.z) | ((unsigned)f2bf(v.w) << 16);
    ((uint2*)Xb)[i] = o;
    return;
  }
  const float* in; u16* out; int Cc, bx, by;
  if (b < 2240) { in = qw;  out = Wt; Cc = 1536; bx = (b - 2048) % 24; by = (b - 2048) / 24; }
  else          { in = pjw; out = Pt; Cc = 512;  bx = (b - 2240) & 7;  by = (b - 2240) >> 3; }
  const int c0 = bx * 64, r0 = by * 64;
  #pragma unroll
  for (int i = 0; i < 16; ++i) {
    int idx = t + i * 256;
    int r = idx >> 6, c = idx & 63;
    tile[c][r] = f2bf(in[(size_t)(r0 + r) * Cc + c0 + c]);
  }
  __syncthreads();
  #pragma unroll
  for (int i = 0; i < 16; ++i) {
    int idx = t + i * 256;
    int r = idx >> 6, c = idx & 63;
    out[(size_t)(c0 + r) * 512 + r0 + c] = tile[r][c];
  }
}

// swizzle for [rows][32] bf16 tiles: chunk 0..3 (16B units), returns u16 index
__device__ __forceinline__ int swz32(int row, int chunk) {
  return row * 32 + ((chunk ^ ((row >> 1) & 3)) << 3);
}
// swizzle for [rows][64] bf16 tiles (128B rows): colByte within row, returns u16 index
__device__ __forceinline__ int swz64(int row, int colByte) {
  return (row * 128 + (colByte ^ ((row & 7) << 4))) >> 1;
}
// K-buffer swizzle: QK^T reads use permuted rows varying in row bits {0,1,3}; XOR those
// bits into the 16B-slot index for bank uniformity.
__device__ __forceinline__ int swzK(int row, int colByte) {
  return (row * 128 + (colByte ^ ((row & 3) << 4) ^ (((row >> 3) & 1) << 6))) >> 1;
}

// ---------------- GEMM core: C[BM x BN] tile, K=512 (lda=ldb=512), BK=32, gload_lds ----
template<int BM, int BN>
__device__ __forceinline__ void gemm_core(const u16* __restrict__ A, const u16* __restrict__ Bt,
                                          int m0, int n0, f32x4 (&acc)[BM/32][BN/32],
                                          u16* lA, u16* lB) {
  const int t = threadIdx.x;
  const int lane = t & 63;
  const int w = t >> 6, wr = w >> 1, wc = w & 1;
  const int lr = lane & 15, lg = lane >> 4;
  char* lAb = (char*)lA + w * 1024;
  char* lBb = (char*)lB + w * 1024;
  #pragma unroll 1
  for (int k0 = 0; k0 < 512; k0 += 32) {
    __syncthreads();
    #pragma unroll
    for (int u = 0; u < BM / 64; ++u) {
      int id = u * 256 + t, row = id >> 2, gc = (id & 3) ^ ((row >> 1) & 3);
      gload16(A + (size_t)(m0 + row) * 512 + k0 + gc * 8, lAb + u * 4096);
    }
    #pragma unroll
    for (int u = 0; u < BN / 64; ++u) {
      int id = u * 256 + t, row = id >> 2, gc = (id & 3) ^ ((row >> 1) & 3);
      gload16(Bt + (size_t)(n0 + row) * 512 + k0 + gc * 8, lBb + u * 4096);
    }
    __syncthreads();
    bf16x8 af[BM / 32], bfr[BN / 32];
    #pragma unroll
    for (int i = 0; i < BM / 32; ++i)
      af[i] = __builtin_bit_cast(bf16x8, *(const uint4*)&lA[swz32(wr * (BM / 2) + i * 16 + lr, lg)]);
    #pragma unroll
    for (int j = 0; j < BN / 32; ++j)
      bfr[j] = __builtin_bit_cast(bf16x8, *(const uint4*)&lB[swz32(wc * (BN / 2) + j * 16 + lr, lg)]);
    #pragma unroll
    for (int i = 0; i < BM / 32; ++i)
      #pragma unroll
      for (int j = 0; j < BN / 32; ++j)
        acc[i][j] = __builtin_amdgcn_mfma_f32_16x16x32_bf16(af[i], bfr[j], acc[i][j], 0, 0, 0);
  }
}

// ---------------- QKV GEMM (128x64 tile) + LDS-staged coalesced scatter --------------
__global__ __launch_bounds__(256, 2) void k_gemm_qkv(const u16* __restrict__ A, const u16* __restrict__ Bt,
                                                     const float* __restrict__ bias,
                                                     u16* __restrict__ Qb, u16* __restrict__ Kb,
                                                     u16* __restrict__ Vtb) {
  __shared__ __align__(16) u16 lA[128 * 32];
  __shared__ __align__(16) u16 lB[64 * 32];
  __shared__ __align__(16) u16 vt[9216];  // Q/K: [128][72]; V: [64][136]
  f32x4 acc[4][2];
  #pragma unroll
  for (int i = 0; i < 4; ++i)
    #pragma unroll
    for (int j = 0; j < 2; ++j) acc[i][j] = (f32x4){0.f, 0.f, 0.f, 0.f};
  const int m0 = blockIdx.x * 128, n0 = blockIdx.y * 64;
  gemm_core<128, 64>(A, Bt, m0, n0, acc, lA, lB);
  const int t = threadIdx.x;
  const int lane = t & 63;
  const int w = t >> 6, wr = w >> 1, wc = w & 1;
  const int lr = lane & 15, lg = lane >> 4;
  const int which = n0 >> 9, h = (n0 >> 6) & 7;
  const int b = m0 >> 11, m0l = m0 & 2047;
  const size_t bh = (size_t)(b * 8 + h);
  if (which != 2) {
    const float scl = (which == 0) ? 0.18033688011112042f : 1.0f;  // Q: 0.125*log2e
    #pragma unroll
    for (int i = 0; i < 4; ++i)
      #pragma unroll
      for (int j = 0; j < 2; ++j) {
        int n = n0 + wc * 32 + j * 16 + lr;
        float bb = bias[n];
        #pragma unroll
        for (int r = 0; r < 4; ++r)
          vt[(wr * 64 + i * 16 + lg * 4 + r) * 72 + wc * 32 + j * 16 + lr] =
              f2bf((acc[i][j][r] + bb) * scl);
      }
    __syncthreads();
    u16* dst = (which == 0 ? Qb : Kb) + (bh * 2048 + m0l) * 64;
    #pragma unroll
    for (int it = 0; it < 4; ++it) {
      int unit = it * 256 + t, row = unit >> 3, ch = unit & 7;
      *(uint4*)&dst[row * 64 + ch * 8] = *(const uint4*)&vt[row * 72 + ch * 8];
    }
  } else {
    #pragma unroll
    for (int i = 0; i < 4; ++i)
      #pragma unroll
      for (int j = 0; j < 2; ++j) {
        int n = n0 + wc * 32 + j * 16 + lr;
        float bb = bias[n];
        uint2 pk;
        pk.x = (unsigned)f2bf(acc[i][j][0] + bb) | ((unsigned)f2bf(acc[i][j][1] + bb) << 16);
        pk.y = (unsigned)f2bf(acc[i][j][2] + bb) | ((unsigned)f2bf(acc[i][j][3] + bb) << 16);
        *(uint2*)&vt[(wc * 32 + j * 16 + lr) * 136 + wr * 64 + i * 16 + lg * 4] = pk;
      }
    __syncthreads();
    u16* dst = Vtb + bh * 64 * 2048 + m0l;
    #pragma unroll
    for (int it = 0; it < 4; ++it) {
      int unit = it * 256 + t, row = unit >> 4, ch = unit & 15;
      *(uint4*)&dst[(size_t)row * 2048 + ch * 8] = *(const uint4*)&vt[row * 136 + ch * 8];
    }
  }
}

// ---------------- proj GEMM (64x64 tile) -> fp32 output ----------------
__global__ __launch_bounds__(256, 2) void k_gemm_proj(const u16* __restrict__ A, const u16* __restrict__ Bt,
                                                      const float* __restrict__ bias,
                                                      float* __restrict__ out) {
  __shared__ __align__(16) u16 lA[64 * 32];
  __shared__ __align__(16) u16 lB[64 * 32];
  f32x4 acc[2][2];
  #pragma unroll
  for (int i = 0; i < 2; ++i)
    #pragma unroll
    for (int j = 0; j < 2; ++j) acc[i][j] = (f32x4){0.f, 0.f, 0.f, 0.f};
  const int m0 = blockIdx.x * 64, n0 = blockIdx.y * 64;
  gemm_core<64, 64>(A, Bt, m0, n0, acc, lA, lB);
  const int lane = threadIdx.x & 63;
  const int w = threadIdx.x >> 6, wr = w >> 1, wc = w & 1;
  const int lr = lane & 15, lg = lane >> 4;
  #pragma unroll
  for (int i = 0; i < 2; ++i)
    #pragma unroll
    for (int j = 0; j < 2; ++j)
      #pragma unroll
      for (int r = 0; r < 4; ++r) {
        int m = m0 + wr * 32 + i * 16 + lg * 4 + r;
        int n = n0 + wc * 32 + j * 16 + lr;
        out[(size_t)m * 512 + n] = acc[i][j][r] + bias[n];
      }
}

// ---------------- flash attention: static-max softmax, 32 q/wave, KV-split=4 ---------
// All-K=32 MFMA pipeline with permuted QK^T A-rows (P lands at k=lg*8+j -> PV K=32
// from registers). K/V staged via global_load_lds with pre-swizzled GLOBAL source
// (linear LDS dest); per-j32 processing keeps live registers under the 4-wave cap.
__global__ __launch_bounds__(256, 4) void k_attn(const u16* __restrict__ Qb, const u16* __restrict__ Kb,
                                                 const u16* __restrict__ Vtb,
                                                 u16* __restrict__ Op, float* __restrict__ Lp) {
  __shared__ __align__(16) u16 smem[16384];  // K dbuf (8KB x2) + V dbuf (8KB x2); epilogue reuse
  u16* Kt0 = smem;
  u16* Kt1 = smem + 4096;
  u16* Vl0 = smem + 8192;
  u16* Vl1 = smem + 12288;
  const int t = threadIdx.x;
  const int lane = t & 63, w = t >> 6;
  const int lr = lane & 15, lg = lane >> 4;
  // flat 1024-block grid -> (qtile, bh, split) with XCD grouping
  const int f = blockIdx.x;
  const int xc = f & 7, jj = f >> 3;
  const int group = xc + ((jj >> 4) << 3);
  const int qtile = jj & 15, bh = group & 15, split = group >> 4;
  const int q0 = qtile * 128 + w * 32;   // wave owns 32 q-rows
  const int sBeg = split * 512;

  bf16x8 qf[2][2];  // [c][half]: B-operand frags, col=q (c*16+lr), k=lg*8+j
  #pragma unroll
  for (int c = 0; c < 2; ++c) {
    const u16* qrow = Qb + ((size_t)bh * 2048 + q0 + c * 16 + lr) * 64;
    qf[c][0] = __builtin_bit_cast(bf16x8, *(const uint4*)(qrow + lg * 8));
    qf[c][1] = __builtin_bit_cast(bf16x8, *(const uint4*)(qrow + 32 + lg * 8));
  }

  f32x4 oacc[2][4], lacc[2];
  #pragma unroll
  for (int c = 0; c < 2; ++c) {
    lacc[c] = (f32x4){0.f, 0.f, 0.f, 0.f};
    #pragma unroll
    for (int ff = 0; ff < 4; ++ff) oacc[c][ff] = (f32x4){0.f, 0.f, 0.f, 0.f};
  }
  bf16x8 ones8;
  #pragma unroll
  for (int k = 0; k < 8; ++k) ones8[k] = (__bf16)1.f;
  const f32x4 NEG12 = (f32x4){-12.f, -12.f, -12.f, -12.f};

  // permuted K row for QK^T A-operand: parity p MFMA covers rows p*4 + (lr>>2)*8 + (lr&3)
  const int prowBase = ((lr >> 2) << 3) + (lr & 3);

  // staging: unit u=t covers LDS rows 0..31, u=t+256 rows 32..63 (linear lane x 16B dest).
  // Global source pre-swizzled so swzK/swz64 LDS reads see K[row][col]/V[row][col].
  const int r0 = t >> 3, j0 = t & 7;
  const int r1 = r0 + 32;
  const int cK = (j0 ^ ((r0 & 3) | (((r0 >> 3) & 1) << 2))) * 8;  // patK(r1)==patK(r0)
  const int cV = (j0 ^ (r0 & 7)) * 8;
  const u16* Kbase = Kb + (size_t)bh * 2048 * 64;
  const u16* Vbase = Vtb + (size_t)bh * 64 * 2048;
  const u16* kg0 = Kbase + (size_t)(sBeg + r0) * 64 + cK;
  const u16* kg1 = Kbase + (size_t)(sBeg + r1) * 64 + cK;
  const u16* vg0 = Vbase + (size_t)r0 * 2048 + sBeg + cV;
  const u16* vg1 = Vbase + (size_t)r1 * 2048 + sBeg + cV;

  // prologue: stage tile 0 into buf0
  gload16(kg0, Kt0 + w * 512);
  gload16(kg1, Kt0 + 2048 + w * 512);
  gload16(vg0, Vl0 + w * 512);
  gload16(vg1, Vl0 + 2048 + w * 512);
  kg0 += 4096; kg1 += 4096; vg0 += 64; vg1 += 64;

  auto TILE = [&](u16* KC, u16* VC, u16* KN, u16* VN) {
    __syncthreads();  // KC/VC staged (vmcnt drained by compiler); KN/VN free
    // issue async stage of next tile (flies across this tile's compute)
    gload16(kg0, KN + w * 512);
    gload16(kg1, KN + 2048 + w * 512);
    gload16(vg0, VN + w * 512);
    gload16(vg1, VN + 2048 + w * 512);
    kg0 += 4096; kg1 += 4096; vg0 += 64; vg1 += 64;
    // per-32-s group: QK^T -> exp2 -> PV, minimal liveness
    #pragma unroll
    for (int j32 = 0; j32 < 2; ++j32) {
      f32x4 sa[2][2];  // [c][p]
      __builtin_amdgcn_s_setprio(1);
      #pragma unroll
      for (int p = 0; p < 2; ++p) {
        const int prow = j32 * 32 + p * 4 + prowBase;
        bf16x8 kb0 = __builtin_bit_cast(bf16x8, *(const uint4*)&KC[swzK(prow, lg * 16)]);
        bf16x8 kb1 = __builtin_bit_cast(bf16x8, *(const uint4*)&KC[swzK(prow, 64 + lg * 16)]);
        #pragma unroll
        for (int c = 0; c < 2; ++c) {
          f32x4 z = mfma32(kb0, qf[c][0], NEG12);
          sa[c][p] = mfma32(kb1, qf[c][1], z);
        }
      }
      __builtin_amdgcn_s_setprio(0);
      // p = 2^(s-12): pb[c][k = p*4+r]
      bf16x8 pb[2];
      #pragma unroll
      for (int c = 0; c < 2; ++c)
        #pragma unroll
        for (int p = 0; p < 2; ++p)
          #pragma unroll
          for (int r = 0; r < 4; ++r)
            pb[c][p * 4 + r] = (__bf16)exp2f(sa[c][p][r]);
      // O^T += V P^T (K=32, P lane-local); l via ones-row MFMA
      __builtin_amdgcn_s_setprio(1);
      lacc[0] = mfma32(ones8, pb[0], lacc[0]);
      lacc[1] = mfma32(ones8, pb[1], lacc[1]);
      #pragma unroll
      for (int ff = 0; ff < 4; ++ff) {
        bf16x8 va = __builtin_bit_cast(bf16x8, *(const uint4*)&VC[swz64(ff * 16 + lr, j32 * 64 + lg * 16)]);
        oacc[0][ff] = mfma32(va, pb[0], oacc[0][ff]);
        oacc[1][ff] = mfma32(va, pb[1], oacc[1][ff]);
      }
      __builtin_amdgcn_s_setprio(0);
    }
  };

  #pragma unroll 1
  for (int tt = 0; tt < 4; ++tt) {
    TILE(Kt0, Vl0, Kt1, Vl1);
    TILE(Kt1, Vl1, Kt0, Vl0);
  }

  // ---- epilogue: stage fp16 partials in LDS [128][72], then full-line Op writes ----
  __syncthreads();  // all K/V LDS reads + in-flight gload_lds done; smem reusable
  #pragma unroll
  for (int c = 0; c < 2; ++c) {
    const int ql = w * 32 + c * 16 + lr;
    #pragma unroll
    for (int ff = 0; ff < 4; ++ff) {
      f16x4 hv;
      hv[0] = (_Float16)oacc[c][ff][0]; hv[1] = (_Float16)oacc[c][ff][1];
      hv[2] = (_Float16)oacc[c][ff][2]; hv[3] = (_Float16)oacc[c][ff][3];
      *(uint2*)&smem[ql * 72 + ff * 16 + lg * 4] = __builtin_bit_cast(uint2, hv);
    }
  }
  __syncthreads();
  {
    u16* dst = Op + ((size_t)(split * 16 + bh) * 2048 + qtile * 128) * 64;
    #pragma unroll
    for (int it = 0; it < 4; ++it) {
      int unit = it * 256 + t, row = unit >> 3, ch = unit & 7;
      *(uint4*)&dst[row * 64 + ch * 8] = *(const uint4*)&smem[row * 72 + ch * 8];
    }
  }
  #pragma unroll
  for (int c = 0; c < 2; ++c) {
    if (lg == 0) {
      const size_t orow = (size_t)((split * 16 + bh) * 2048) + q0 + c * 16 + lr;
      Lp[orow] = lacc[c][0];  // all rows of lacc equal (ones-row MFMA)
    }
  }
}

// ---------------- combine 4 KV-splits (shared static max) -> AO bf16 ----------------
__global__ void k_combine(const u16* __restrict__ Op, const float* __restrict__ Lp,
                          u16* __restrict__ AO) {
  int idx = blockIdx.x * 256 + threadIdx.x;  // 32768 rows * 8 chunks
  int chunk = idx & 7, row = idx >> 3;
  float den = Lp[row] + Lp[32768 + row] + Lp[65536 + row] + Lp[98304 + row];
  float inv = 1.0f / den;
  float o[8];
  #pragma unroll
  for (int k = 0; k < 8; ++k) o[k] = 0.f;
  #pragma unroll
  for (int s = 0; s < 4; ++s) {
    uint4 u = ((const uint4*)Op)[(size_t)s * 262144 + row * 8 + chunk];
    f16x8 hv = __builtin_bit_cast(f16x8, u);
    #pragma unroll
    for (int k = 0; k < 8; ++k) o[k] += (float)hv[k];
  }
  bf16x8 bv;
  #pragma unroll
  for (int k = 0; k < 8; ++k) bv[k] = (__bf16)(o[k] * inv);
  int bh = row >> 11, q = row & 2047, bb = bh >> 3, h = bh & 7;
  *(uint4*)&AO[((size_t)(bb * 2048 + q)) * 512 + h * 64 + chunk * 8] = __builtin_bit_cast(uint4, bv);
}

extern "C" void kernel_launch(void* const* d_in, const int* in_sizes, int n_in,
                              void* d_out, int out_size, void* d_ws, size_t ws_size,
                              hipStream_t stream) {
  (void)in_sizes; (void)n_in; (void)out_size; (void)ws_size;
  const float* x      = (const float*)d_in[0];
  const float* qkv_w  = (const float*)d_in[1];
  const float* qkv_b  = (const float*)d_in[2];
  const float* proj_w = (const float*)d_in[3];
  const float* proj_b = (const float*)d_in[4];
  float* out = (float*)d_out;
  char* wsc = (char*)d_ws;
  // Lp overlaps the Xb region (Xb dead after k_gemm_qkv; Lp written by k_attn later).
  float* Lp  = (float*)(wsc + 0);        // [4][16][2048] f32 (524,288 B)
  u16*   Xb  = (u16*)(wsc + 0);          // 4096x512 bf16       (4,194,304 B)
  u16*   Wt  = (u16*)(wsc + 4194304);    // 1536x512 bf16 (W^T) (1,572,864 B)
  u16*   Pt  = (u16*)(wsc + 5767168);    // 512x512 bf16 (W^T)  (  524,288 B)
  u16*   Qb  = (u16*)(wsc + 6291456);    // [16][2048][64] bf16 (4,194,304 B)
  u16*   Kb  = (u16*)(wsc + 10485760);   // [16][2048][64] bf16
  u16*   Vtb = (u16*)(wsc + 14680064);   // [16][64][2048] bf16
  u16*   AO  = (u16*)(wsc + 18874368);   // 4096x512 bf16
  u16*   Op  = (u16*)(wsc + 23068672);   // [4][16][2048][64] fp16 (16,777,216 B) -> end 39,845,888

  k_prep<<<2304, 256, 0, stream>>>(x, qkv_w, proj_w, Xb, Wt, Pt);
  k_gemm_qkv<<<dim3(32, 24), 256, 0, stream>>>(Xb, Wt, qkv_b, Qb, Kb, Vtb);
  k_attn<<<1024, 256, 0, stream>>>(Qb, Kb, Vtb, Op, Lp);
  k_combine<<<1024, 256, 0, stream>>>(Op, Lp, AO);
  k_gemm_proj<<<dim3(64, 8), 256, 0, stream>>>(AO, Pt, proj_b, out);
}

// Round 10
// 60.213 us; speedup vs baseline: 2.0801x; 1.0504x over previous
//
#include <hip/hip_runtime.h>
#include <stdint.h>

typedef unsigned short u16;
typedef __bf16 bf16x8 __attribute__((ext_vector_type(8)));
typedef _Float16 f16x4 __attribute__((ext_vector_type(4)));
typedef _Float16 f16x8 __attribute__((ext_vector_type(8)));
typedef float  f32x4  __attribute__((ext_vector_type(4)));

__device__ __forceinline__ u16 f2bf(float f) {
  union { float f; unsigned u; } v; v.f = f;
  unsigned r = v.u + 0x7FFFu + ((v.u >> 16) & 1u);
  return (u16)(r >> 16);
}

__device__ __forceinline__ void gload16(const void* g, void* l) {
  __builtin_amdgcn_global_load_lds((const __attribute__((address_space(1))) unsigned int*)g,
                                   (__attribute__((address_space(3))) unsigned int*)l, 16, 0, 0);
}

__device__ __forceinline__ f32x4 mfma32(bf16x8 a, bf16x8 b, f32x4 c) {
  return __builtin_amdgcn_mfma_f32_16x16x32_bf16(a, b, c, 0, 0, 0);
}

// ---------------- fused prep: x->bf16 convert + both weight transposes ----------------
__global__ void k_prep(const float* __restrict__ x, const float* __restrict__ qw,
                       const float* __restrict__ pjw, u16* __restrict__ Xb,
                       u16* __restrict__ Wt, u16* __restrict__ Pt) {
  __shared__ u16 tile[64][65];
  const int b = blockIdx.x, t = threadIdx.x;
  if (b < 2048) {
    int i = b * 256 + t;
    float4 v = ((const float4*)x)[i];
    uint2 o;
    o.x = (unsigned)f2bf(v.x) | ((unsigned)f2bf(v.y) << 16);
    o.y = (unsigned)f2bf(v.z) | ((unsigned)f2bf(v.w) << 16);
    ((uint2*)Xb)[i] = o;
    return;
  }
  const float* in; u16* out; int Cc, bx, by;
  if (b < 2240) { in = qw;  out = Wt; Cc = 1536; bx = (b - 2048) % 24; by = (b - 2048) / 24; }
  else          { in = pjw; out = Pt; Cc = 512;  bx = (b - 2240) & 7;  by = (b - 2240) >> 3; }
  const int c0 = bx * 64, r0 = by * 64;
  #pragma unroll
  for (int i = 0; i < 16; ++i) {
    int idx = t + i * 256;
    int r = idx >> 6, c = idx & 63;
    tile[c][r] = f2bf(in[(size_t)(r0 + r) * Cc + c0 + c]);
  }
  __syncthreads();
  #pragma unroll
  for (int i = 0; i < 16; ++i) {
    int idx = t + i * 256;
    int r = idx >> 6, c = idx & 63;
    out[(size_t)(c0 + r) * 512 + r0 + c] = tile[r][c];
  }
}

// swizzle for [rows][64] bf16 tiles (128B rows): colByte within row, returns u16 index
__device__ __forceinline__ int swz64(int row, int colByte) {
  return (row * 128 + (colByte ^ ((row & 7) << 4))) >> 1;
}
// K-buffer swizzle (attn): QK^T permuted rows vary in bits {0,1,3}
__device__ __forceinline__ int swzK(int row, int colByte) {
  return (row * 128 + (colByte ^ ((row & 3) << 4) ^ (((row >> 3) & 1) << 6))) >> 1;
}

// ---------------- GEMM core: C[BM x BN], K=512 (lda=ldb=512), BK=64, gload_lds --------
// LDS layout [rows][64] with swz64; global source pre-swizzled with the same involution.
template<int BM, int BN>
__device__ __forceinline__ void gemm_core(const u16* __restrict__ A, const u16* __restrict__ Bt,
                                          int m0, int n0, f32x4 (&acc)[BM/32][BN/32],
                                          u16* lA, u16* lB) {
  const int t = threadIdx.x;
  const int lane = t & 63;
  const int w = t >> 6, wr = w >> 1, wc = w & 1;
  const int lr = lane & 15, lg = lane >> 4;
  const int r0 = t >> 3, j0 = t & 7;
  const int cA = (j0 ^ (r0 & 7)) * 8;  // pre-swizzled column (elems), row&7 == r0&7
  #pragma unroll 1
  for (int k0 = 0; k0 < 512; k0 += 64) {
    __syncthreads();
    #pragma unroll
    for (int u = 0; u < BM / 32; ++u)
      gload16(A + (size_t)(m0 + u * 32 + r0) * 512 + k0 + cA, (char*)lA + u * 4096 + w * 1024);
    #pragma unroll
    for (int u = 0; u < BN / 32; ++u)
      gload16(Bt + (size_t)(n0 + u * 32 + r0) * 512 + k0 + cA, (char*)lB + u * 4096 + w * 1024);
    __syncthreads();
    #pragma unroll
    for (int kh = 0; kh < 2; ++kh) {
      bf16x8 af[BM / 32], bfr[BN / 32];
      #pragma unroll
      for (int i = 0; i < BM / 32; ++i)
        af[i] = __builtin_bit_cast(bf16x8, *(const uint4*)&lA[swz64(wr * (BM / 2) + i * 16 + lr, kh * 64 + lg * 16)]);
      #pragma unroll
      for (int j = 0; j < BN / 32; ++j)
        bfr[j] = __builtin_bit_cast(bf16x8, *(const uint4*)&lB[swz64(wc * (BN / 2) + j * 16 + lr, kh * 64 + lg * 16)]);
      #pragma unroll
      for (int i = 0; i < BM / 32; ++i)
        #pragma unroll
        for (int j = 0; j < BN / 32; ++j)
          acc[i][j] = mfma32(af[i], bfr[j], acc[i][j]);
    }
  }
}

// ---------------- QKV GEMM (128x64 tile) + LDS-staged coalesced scatter --------------
__global__ __launch_bounds__(256, 2) void k_gemm_qkv(const u16* __restrict__ A, const u16* __restrict__ Bt,
                                                     const float* __restrict__ bias,
                                                     u16* __restrict__ Qb, u16* __restrict__ Kb,
                                                     u16* __restrict__ Vtb) {
  __shared__ __align__(16) u16 lA[128 * 64];
  __shared__ __align__(16) u16 lB[64 * 64];
  __shared__ __align__(16) u16 vt[9216];  // Q/K: [128][72]; V: [64][136]
  f32x4 acc[4][2];
  #pragma unroll
  for (int i = 0; i < 4; ++i)
    #pragma unroll
    for (int j = 0; j < 2; ++j) acc[i][j] = (f32x4){0.f, 0.f, 0.f, 0.f};
  const int m0 = blockIdx.x * 128, n0 = blockIdx.y * 64;
  gemm_core<128, 64>(A, Bt, m0, n0, acc, lA, lB);
  const int t = threadIdx.x;
  const int lane = t & 63;
  const int w = t >> 6, wr = w >> 1, wc = w & 1;
  const int lr = lane & 15, lg = lane >> 4;
  const int which = n0 >> 9, h = (n0 >> 6) & 7;
  const int b = m0 >> 11, m0l = m0 & 2047;
  const size_t bh = (size_t)(b * 8 + h);
  if (which != 2) {
    const float scl = (which == 0) ? 0.18033688011112042f : 1.0f;  // Q: 0.125*log2e
    #pragma unroll
    for (int i = 0; i < 4; ++i)
      #pragma unroll
      for (int j = 0; j < 2; ++j) {
        int n = n0 + wc * 32 + j * 16 + lr;
        float bb = bias[n];
        #pragma unroll
        for (int r = 0; r < 4; ++r)
          vt[(wr * 64 + i * 16 + lg * 4 + r) * 72 + wc * 32 + j * 16 + lr] =
              f2bf((acc[i][j][r] + bb) * scl);
      }
    __syncthreads();
    u16* dst = (which == 0 ? Qb : Kb) + (bh * 2048 + m0l) * 64;
    #pragma unroll
    for (int it = 0; it < 4; ++it) {
      int unit = it * 256 + t, row = unit >> 3, ch = unit & 7;
      *(uint4*)&dst[row * 64 + ch * 8] = *(const uint4*)&vt[row * 72 + ch * 8];
    }
  } else {
    #pragma unroll
    for (int i = 0; i < 4; ++i)
      #pragma unroll
      for (int j = 0; j < 2; ++j) {
        int n = n0 + wc * 32 + j * 16 + lr;
        float bb = bias[n];
        uint2 pk;
        pk.x = (unsigned)f2bf(acc[i][j][0] + bb) | ((unsigned)f2bf(acc[i][j][1] + bb) << 16);
        pk.y = (unsigned)f2bf(acc[i][j][2] + bb) | ((unsigned)f2bf(acc[i][j][3] + bb) << 16);
        *(uint2*)&vt[(wc * 32 + j * 16 + lr) * 136 + wr * 64 + i * 16 + lg * 4] = pk;
      }
    __syncthreads();
    u16* dst = Vtb + bh * 64 * 2048 + m0l;
    #pragma unroll
    for (int it = 0; it < 4; ++it) {
      int unit = it * 256 + t, row = unit >> 4, ch = unit & 15;
      *(uint4*)&dst[(size_t)row * 2048 + ch * 8] = *(const uint4*)&vt[row * 136 + ch * 8];
    }
  }
}

// ---------------- proj GEMM (64x64 tile) -> fp32 output ----------------
__global__ __launch_bounds__(256, 2) void k_gemm_proj(const u16* __restrict__ A, const u16* __restrict__ Bt,
                                                      const float* __restrict__ bias,
                                                      float* __restrict__ out) {
  __shared__ __align__(16) u16 lA[64 * 64];
  __shared__ __align__(16) u16 lB[64 * 64];
  f32x4 acc[2][2];
  #pragma unroll
  for (int i = 0; i < 2; ++i)
    #pragma unroll
    for (int j = 0; j < 2; ++j) acc[i][j] = (f32x4){0.f, 0.f, 0.f, 0.f};
  const int m0 = blockIdx.x * 64, n0 = blockIdx.y * 64;
  gemm_core<64, 64>(A, Bt, m0, n0, acc, lA, lB);
  const int lane = threadIdx.x & 63;
  const int w = threadIdx.x >> 6, wr = w >> 1, wc = w & 1;
  const int lr = lane & 15, lg = lane >> 4;
  #pragma unroll
  for (int i = 0; i < 2; ++i)
    #pragma unroll
    for (int j = 0; j < 2; ++j)
      #pragma unroll
      for (int r = 0; r < 4; ++r) {
        int m = m0 + wr * 32 + i * 16 + lg * 4 + r;
        int n = n0 + wc * 32 + j * 16 + lr;
        out[(size_t)m * 512 + n] = acc[i][j][r] + bias[n];
      }
}

// ---------------- flash attention: static-max softmax, 8 waves x 32 q, KV-split=4 ----
// All-K=32 MFMA with permuted QK^T A-rows (P lands at k=lg*8+j -> PV K=32 from regs).
// 256 q-rows per block so each staged K/V tile feeds 8 waves; 512-block grid (2/CU).
__global__ __launch_bounds__(512, 4) void k_attn(const u16* __restrict__ Qb, const u16* __restrict__ Kb,
                                                 const u16* __restrict__ Vtb,
                                                 u16* __restrict__ Op, float* __restrict__ Lp) {
  __shared__ __align__(16) u16 smem[18432];  // main: K dbuf 16KB + V dbuf 16KB; epi: [256][72]
  u16* Kt0 = smem;
  u16* Kt1 = smem + 4096;
  u16* Vl0 = smem + 8192;
  u16* Vl1 = smem + 12288;
  const int t = threadIdx.x;
  const int lane = t & 63, w = t >> 6;
  const int lr = lane & 15, lg = lane >> 4;
  // flat 512-block grid -> (qtile, bh, split) with XCD grouping:
  // XCD c = f&7 owns 8 (bh,split) groups; 8 qtile-members each.
  const int f = blockIdx.x;
  const int xc = f & 7, jj = f >> 3;
  const int group = xc + ((jj >> 3) << 3);
  const int qtile = jj & 7, bh = group & 15, split = group >> 4;
  const int q0 = qtile * 256 + w * 32;   // wave owns 32 q-rows
  const int sBeg = split * 512;

  bf16x8 qf[2][2];  // [c][half]: B-operand frags, col=q (c*16+lr), k=lg*8+j
  #pragma unroll
  for (int c = 0; c < 2; ++c) {
    const u16* qrow = Qb + ((size_t)bh * 2048 + q0 + c * 16 + lr) * 64;
    qf[c][0] = __builtin_bit_cast(bf16x8, *(const uint4*)(qrow + lg * 8));
    qf[c][1] = __builtin_bit_cast(bf16x8, *(const uint4*)(qrow + 32 + lg * 8));
  }

  f32x4 oacc[2][4], lacc[2];
  #pragma unroll
  for (int c = 0; c < 2; ++c) {
    lacc[c] = (f32x4){0.f, 0.f, 0.f, 0.f};
    #pragma unroll
    for (int ff = 0; ff < 4; ++ff) oacc[c][ff] = (f32x4){0.f, 0.f, 0.f, 0.f};
  }
  bf16x8 ones8;
  #pragma unroll
  for (int k = 0; k < 8; ++k) ones8[k] = (__bf16)1.f;
  const f32x4 NEG12 = (f32x4){-12.f, -12.f, -12.f, -12.f};

  // permuted K row for QK^T A-operand: parity p MFMA covers rows p*4 + (lr>>2)*8 + (lr&3)
  const int prowBase = ((lr >> 2) << 3) + (lr & 3);

  // staging: 512 threads x 16B = one 8KB tile per issue; linear LDS dest (base + w*1KB),
  // global source pre-swizzled to match swzK/swz64 reads.
  const int r0 = t >> 3, j0 = t & 7;
  const int cK = (j0 ^ ((r0 & 3) | (((r0 >> 3) & 1) << 2))) * 8;
  const int cV = (j0 ^ (r0 & 7)) * 8;
  const u16* Kbase = Kb + (size_t)bh * 2048 * 64;
  const u16* Vbase = Vtb + (size_t)bh * 64 * 2048;
  const u16* kg0 = Kbase + (size_t)(sBeg + r0) * 64 + cK;
  const u16* vg0 = Vbase + (size_t)r0 * 2048 + sBeg + cV;

  // prologue: stage tile 0 into buf0
  gload16(kg0, Kt0 + w * 512);
  gload16(vg0, Vl0 + w * 512);
  kg0 += 4096; vg0 += 64;

  auto TILE = [&](u16* KC, u16* VC, u16* KN, u16* VN) {
    __syncthreads();  // KC/VC staged (vmcnt drained before barrier); KN/VN free
    // issue async stage of next tile (flies across this tile's compute)
    gload16(kg0, KN + w * 512);
    gload16(vg0, VN + w * 512);
    kg0 += 4096; vg0 += 64;
    #pragma unroll
    for (int j32 = 0; j32 < 2; ++j32) {
      f32x4 sa[2][2];  // [c][p]
      __builtin_amdgcn_s_setprio(1);
      #pragma unroll
      for (int p = 0; p < 2; ++p) {
        const int prow = j32 * 32 + p * 4 + prowBase;
        bf16x8 kb0 = __builtin_bit_cast(bf16x8, *(const uint4*)&KC[swzK(prow, lg * 16)]);
        bf16x8 kb1 = __builtin_bit_cast(bf16x8, *(const uint4*)&KC[swzK(prow, 64 + lg * 16)]);
        #pragma unroll
        for (int c = 0; c < 2; ++c) {
          f32x4 z = mfma32(kb0, qf[c][0], NEG12);
          sa[c][p] = mfma32(kb1, qf[c][1], z);
        }
      }
      __builtin_amdgcn_s_setprio(0);
      // p = 2^(s-12): pb[c][k = p*4+r]
      bf16x8 pb[2];
      #pragma unroll
      for (int c = 0; c < 2; ++c)
        #pragma unroll
        for (int p = 0; p < 2; ++p)
          #pragma unroll
          for (int r = 0; r < 4; ++r)
            pb[c][p * 4 + r] = (__bf16)exp2f(sa[c][p][r]);
      // O^T += V P^T (K=32, P lane-local); l via ones-row MFMA
      __builtin_amdgcn_s_setprio(1);
      lacc[0] = mfma32(ones8, pb[0], lacc[0]);
      lacc[1] = mfma32(ones8, pb[1], lacc[1]);
      #pragma unroll
      for (int ff = 0; ff < 4; ++ff) {
        bf16x8 va = __builtin_bit_cast(bf16x8, *(const uint4*)&VC[swz64(ff * 16 + lr, j32 * 64 + lg * 16)]);
        oacc[0][ff] = mfma32(va, pb[0], oacc[0][ff]);
        oacc[1][ff] = mfma32(va, pb[1], oacc[1][ff]);
      }
      __builtin_amdgcn_s_setprio(0);
    }
  };

  #pragma unroll 1
  for (int tt = 0; tt < 4; ++tt) {
    TILE(Kt0, Vl0, Kt1, Vl1);
    TILE(Kt1, Vl1, Kt0, Vl0);
  }

  // ---- epilogue: stage fp16 partials in LDS [256][72], then full-line Op writes ----
  __syncthreads();  // all K/V LDS reads + in-flight gload_lds done; smem reusable
  #pragma unroll
  for (int c = 0; c < 2; ++c) {
    const int ql = w * 32 + c * 16 + lr;
    #pragma unroll
    for (int ff = 0; ff < 4; ++ff) {
      f16x4 hv;
      hv[0] = (_Float16)oacc[c][ff][0]; hv[1] = (_Float16)oacc[c][ff][1];
      hv[2] = (_Float16)oacc[c][ff][2]; hv[3] = (_Float16)oacc[c][ff][3];
      *(uint2*)&smem[ql * 72 + ff * 16 + lg * 4] = __builtin_bit_cast(uint2, hv);
    }
  }
  __syncthreads();
  {
    u16* dst = Op + ((size_t)(split * 16 + bh) * 2048 + qtile * 256) * 64;
    #pragma unroll
    for (int it = 0; it < 4; ++it) {
      int unit = it * 512 + t, row = unit >> 3, ch = unit & 7;
      *(uint4*)&dst[row * 64 + ch * 8] = *(const uint4*)&smem[row * 72 + ch * 8];
    }
  }
  #pragma unroll
  for (int c = 0; c < 2; ++c) {
    if (lg == 0) {
      const size_t orow = (size_t)((split * 16 + bh) * 2048) + q0 + c * 16 + lr;
      Lp[orow] = lacc[c][0];  // all rows of lacc equal (ones-row MFMA)
    }
  }
}

// ---------------- combine 4 KV-splits (shared static max) -> AO bf16 ----------------
__global__ void k_combine(const u16* __restrict__ Op, const float* __restrict__ Lp,
                          u16* __restrict__ AO) {
  int idx = blockIdx.x * 256 + threadIdx.x;  // 32768 rows * 8 chunks
  int chunk = idx & 7, row = idx >> 3;
  float den = Lp[row] + Lp[32768 + row] + Lp[65536 + row] + Lp[98304 + row];
  float inv = 1.0f / den;
  float o[8];
  #pragma unroll
  for (int k = 0; k < 8; ++k) o[k] = 0.f;
  #pragma unroll
  for (int s = 0; s < 4; ++s) {
    uint4 u = ((const uint4*)Op)[(size_t)s * 262144 + row * 8 + chunk];
    f16x8 hv = __builtin_bit_cast(f16x8, u);
    #pragma unroll
    for (int k = 0; k < 8; ++k) o[k] += (float)hv[k];
  }
  bf16x8 bv;
  #pragma unroll
  for (int k = 0; k < 8; ++k) bv[k] = (__bf16)(o[k] * inv);
  int bh = row >> 11, q = row & 2047, bb = bh >> 3, h = bh & 7;
  *(uint4*)&AO[((size_t)(bb * 2048 + q)) * 512 + h * 64 + chunk * 8] = __builtin_bit_cast(uint4, bv);
}

extern "C" void kernel_launch(void* const* d_in, const int* in_sizes, int n_in,
                              void* d_out, int out_size, void* d_ws, size_t ws_size,
                              hipStream_t stream) {
  (void)in_sizes; (void)n_in; (void)out_size; (void)ws_size;
  const float* x      = (const float*)d_in[0];
  const float* qkv_w  = (const float*)d_in[1];
  const float* qkv_b  = (const float*)d_in[2];
  const float* proj_w = (const float*)d_in[3];
  const float* proj_b = (const float*)d_in[4];
  float* out = (float*)d_out;
  char* wsc = (char*)d_ws;
  // Lp overlaps the Xb region (Xb dead after k_gemm_qkv; Lp written by k_attn later).
  float* Lp  = (float*)(wsc + 0);        // [4][16][2048] f32 (524,288 B)
  u16*   Xb  = (u16*)(wsc + 0);          // 4096x512 bf16       (4,194,304 B)
  u16*   Wt  = (u16*)(wsc + 4194304);    // 1536x512 bf16 (W^T) (1,572,864 B)
  u16*   Pt  = (u16*)(wsc + 5767168);    // 512x512 bf16 (W^T)  (  524,288 B)
  u16*   Qb  = (u16*)(wsc + 6291456);    // [16][2048][64] bf16 (4,194,304 B)
  u16*   Kb  = (u16*)(wsc + 10485760);   // [16][2048][64] bf16
  u16*   Vtb = (u16*)(wsc + 14680064);   // [16][64][2048] bf16
  u16*   AO  = (u16*)(wsc + 18874368);   // 4096x512 bf16
  u16*   Op  = (u16*)(wsc + 23068672);   // [4][16][2048][64] fp16 (16,777,216 B) -> end 39,845,888

  k_prep<<<2304, 256, 0, stream>>>(x, qkv_w, proj_w, Xb, Wt, Pt);
  k_gemm_qkv<<<dim3(32, 24), 256, 0, stream>>>(Xb, Wt, qkv_b, Qb, Kb, Vtb);
  k_attn<<<512, 512, 0, stream>>>(Qb, Kb, Vtb, Op, Lp);
  k_combine<<<1024, 256, 0, stream>>>(Op, Lp, AO);
  k_gemm_proj<<<dim3(64, 8), 256, 0, stream>>>(AO, Pt, proj_b, out);
}